// Round 1
// baseline (12211.296 us; speedup 1.0000x reference)
//
#include <hip/hip_runtime.h>
#include <stdint.h>

// Problem constants (fixed by the reference): B=64, T=512, I=256, H=512, L=2
#define Bn 64
#define Tn 512
#define In 256
#define Hn 512
#define NBLK 64                    // 32 blocks layer0 + 32 blocks layer1
#define OUT_HT 16777216            // B*T*H  (start of hT)
#define OUT_CT 16842752            // OUT_HT + 2*B*H (start of cT)

// Workspace layout (bytes):
//   0        h0buf[2][B][H] bf16   (131072)
//   131072   h1buf[2][B][H] bf16   (131072)
//   262144   barrier counters      (4096; 1024 uints, use [0..511])
//   266240   wx0 bf16 (2048x256)   (1048576)
//   1314816  wh0 bf16 (2048x512)   (2097152)
//   3411968  wx1 bf16 (2048x512)   (2097152)
//   5509120  wh1 bf16 (2048x512)   (2097152)
//   total    7606272 bytes

typedef __attribute__((ext_vector_type(8))) short bf16x8;   // 8 bf16 = 4 VGPRs (guide-verified frag type)
typedef __attribute__((ext_vector_type(4))) float f32x4;

__device__ __forceinline__ unsigned short f2bf(float f) {   // fp32 -> bf16 RNE
    unsigned u = __float_as_uint(f);
    return (unsigned short)((u + 0x7fffu + ((u >> 16) & 1u)) >> 16);
}
__device__ __forceinline__ float sigm(float v) { return 1.0f / (1.0f + __expf(-v)); }
__device__ __forceinline__ float tanhv(float v) { float e = __expf(2.0f * v); return 1.0f - 2.0f / (e + 1.0f); }

__global__ void lstm_prep(const float* __restrict__ wxh0, const float* __restrict__ whh0,
                          const float* __restrict__ wxh1, const float* __restrict__ whh1,
                          unsigned short* __restrict__ wx0b, unsigned short* __restrict__ wh0b,
                          unsigned short* __restrict__ wx1b, unsigned short* __restrict__ wh1b,
                          unsigned int* __restrict__ zr) {
    int tid = blockIdx.x * blockDim.x + threadIdx.x;
    int stride = gridDim.x * blockDim.x;
    for (int n = tid; n < 2048 * 256; n += stride) wx0b[n] = f2bf(wxh0[n]);
    for (int n = tid; n < 2048 * 512; n += stride) {
        wh0b[n] = f2bf(whh0[n]);
        wx1b[n] = f2bf(wxh1[n]);
        wh1b[n] = f2bf(whh1[n]);
    }
    // zero h double-buffers (as uints) + barrier counters: 266240/4 = 66560
    for (int n = tid; n < 66560; n += stride) zr[n] = 0u;
}

__launch_bounds__(256, 1)
__global__ void lstm_main(const float* __restrict__ x,
                          const unsigned short* __restrict__ wx0,
                          const unsigned short* __restrict__ wh0,
                          const unsigned short* __restrict__ wx1,
                          const unsigned short* __restrict__ wh1,
                          const float* __restrict__ bx0, const float* __restrict__ bh0,
                          const float* __restrict__ bx1, const float* __restrict__ bh1,
                          float* __restrict__ out,
                          unsigned short* __restrict__ h0b,
                          unsigned short* __restrict__ h1b,
                          unsigned int* __restrict__ bar) {
    const int layer = blockIdx.x >> 5;        // 0 or 1
    const int cb    = blockIdx.x & 31;        // column-group: owns h cols [cb*16, cb*16+16)
    const int wv    = threadIdx.x >> 6;       // wave 0..3 -> row tile [16*wv, 16*wv+16)
    const int lane  = threadIdx.x & 63;
    const int quad  = lane >> 4;
    const int ln    = lane & 15;
    const int row0  = wv << 4;
    const int colh  = (cb << 4) + ln;         // this lane's h column (also acc col)

    // bias per gate chunk (col-only -> same for all 4 acc rows of a lane)
    float bias[4];
#pragma unroll
    for (int q = 0; q < 4; ++q) {
        int gc = q * Hn + colh;
        bias[q] = (layer == 0) ? (bx0[gc] + bh0[gc]) : (bx1[gc] + bh1[gc]);
    }

    // B-fragment base pointers: W[gc][k] row-major, lane reads 8 contiguous k
    const unsigned short* wbp[4];  // x-part weights (layer0: K=In ld; layer1: K=Hn ld)
    const unsigned short* whp[4];  // h-part weights
#pragma unroll
    for (int q = 0; q < 4; ++q) {
        int gc = q * Hn + colh;
        wbp[q] = (layer == 0) ? (wx0 + (size_t)gc * In + quad * 8)
                              : (wx1 + (size_t)gc * Hn + quad * 8);
        whp[q] = ((layer == 0) ? wh0 : wh1) + (size_t)gc * Hn + quad * 8;
    }

    // A-fragment row bases: lane reads row (row0+ln), 8 contiguous k at quad*8
    const float* xrow0 = x + (size_t)(row0 + ln) * Tn * In + quad * 8;
    const int hoff = (row0 + ln) * Hn + quad * 8;

    float c[4] = {0.f, 0.f, 0.f, 0.f};  // cell state, rows row0+quad*4+r, col colh

    for (int p = 0; p <= Tn; ++p) {
        const int t = (layer == 0) ? p : (p - 1);        // pipelined: L1 runs one step behind
        const bool active = (layer == 0) ? (p < Tn) : (p >= 1);
        const int wrb = p & 1;        // buffer written this phase
        const int rdb = wrb ^ 1;      // buffer written last phase

        if (active) {
            f32x4 acc[4];
#pragma unroll
            for (int q = 0; q < 4; ++q) acc[q] = (f32x4){bias[q], bias[q], bias[q], bias[q]};

            if (layer == 0) {
                // x part: K = 256 (fp32 -> bf16 in-register)
                const float* xr = xrow0 + (size_t)t * In;
#pragma unroll 4
                for (int kk = 0; kk < In; kk += 32) {
                    f32x4 xa = *(const f32x4*)(xr + kk);
                    f32x4 xc = *(const f32x4*)(xr + kk + 4);
                    bf16x8 a;
                    a[0] = (short)f2bf(xa[0]); a[1] = (short)f2bf(xa[1]);
                    a[2] = (short)f2bf(xa[2]); a[3] = (short)f2bf(xa[3]);
                    a[4] = (short)f2bf(xc[0]); a[5] = (short)f2bf(xc[1]);
                    a[6] = (short)f2bf(xc[2]); a[7] = (short)f2bf(xc[3]);
#pragma unroll
                    for (int q = 0; q < 4; ++q) {
                        bf16x8 b = *(const bf16x8*)(wbp[q] + kk);
                        acc[q] = __builtin_amdgcn_mfma_f32_16x16x32_bf16(a, b, acc[q], 0, 0, 0);
                    }
                }
                // h part: K = 512
                const unsigned short* hr = h0b + rdb * (Bn * Hn) + hoff;
#pragma unroll 4
                for (int kk = 0; kk < Hn; kk += 32) {
                    bf16x8 a = *(const bf16x8*)(hr + kk);
#pragma unroll
                    for (int q = 0; q < 4; ++q) {
                        bf16x8 b = *(const bf16x8*)(whp[q] + kk);
                        acc[q] = __builtin_amdgcn_mfma_f32_16x16x32_bf16(a, b, acc[q], 0, 0, 0);
                    }
                }
            } else {
                // layer1 input part: h0(t) written by layer0 last phase; K = 512
                const unsigned short* h0r = h0b + rdb * (Bn * Hn) + hoff;
#pragma unroll 4
                for (int kk = 0; kk < Hn; kk += 32) {
                    bf16x8 a = *(const bf16x8*)(h0r + kk);
#pragma unroll
                    for (int q = 0; q < 4; ++q) {
                        bf16x8 b = *(const bf16x8*)(wbp[q] + kk);
                        acc[q] = __builtin_amdgcn_mfma_f32_16x16x32_bf16(a, b, acc[q], 0, 0, 0);
                    }
                }
                // layer1 recurrent part: h1(t-1); K = 512
                const unsigned short* h1r = h1b + rdb * (Bn * Hn) + hoff;
#pragma unroll 4
                for (int kk = 0; kk < Hn; kk += 32) {
                    bf16x8 a = *(const bf16x8*)(h1r + kk);
#pragma unroll
                    for (int q = 0; q < 4; ++q) {
                        bf16x8 b = *(const bf16x8*)(whp[q] + kk);
                        acc[q] = __builtin_amdgcn_mfma_f32_16x16x32_bf16(a, b, acc[q], 0, 0, 0);
                    }
                }
            }

            // LSTM cell, per-lane: acc rows row0+quad*4+r, col colh
            unsigned short* hw = ((layer == 0) ? h0b : h1b) + wrb * (Bn * Hn);
#pragma unroll
            for (int r = 0; r < 4; ++r) {
                int row = row0 + quad * 4 + r;
                float ig = sigm(acc[0][r]);
                float fg = sigm(acc[1][r]);
                float gg = tanhv(acc[2][r]);
                float og = sigm(acc[3][r]);
                float cy = c[r] * fg + ig * gg;
                float hy = og * tanhv(cy);
                c[r] = cy;
                hw[row * Hn + colh] = f2bf(hy);
                if (layer == 1) out[(size_t)row * (Tn * Hn) + (size_t)t * Hn + colh] = hy;
                if (t == Tn - 1) {
                    out[OUT_HT + layer * (Bn * Hn) + row * Hn + colh] = hy;
                    out[OUT_CT + layer * (Bn * Hn) + row * Hn + colh] = cy;
                }
            }
        }

        // grid barrier after every phase except the last
        if (p < Tn) {
            __syncthreads();   // compiler drains vmcnt before s_barrier -> all block stores in L2
            if (threadIdx.x == 0) {
                __builtin_amdgcn_fence(__ATOMIC_RELEASE, "agent");   // flush XCD L2 (cross-XCD visibility)
                __hip_atomic_fetch_add(&bar[p], 1u, __ATOMIC_RELAXED, __HIP_MEMORY_SCOPE_AGENT);
                while (__hip_atomic_load(&bar[p], __ATOMIC_RELAXED, __HIP_MEMORY_SCOPE_AGENT)
                       < (unsigned)gridDim.x) {
                    __builtin_amdgcn_s_sleep(1);
                }
                __builtin_amdgcn_fence(__ATOMIC_ACQUIRE, "agent");   // invalidate stale L1/L2 lines
            }
            __syncthreads();
        }
    }
}

extern "C" void kernel_launch(void* const* d_in, const int* in_sizes, int n_in,
                              void* d_out, int out_size, void* d_ws, size_t ws_size,
                              hipStream_t stream) {
    const float* x    = (const float*)d_in[0];
    const float* wxh0 = (const float*)d_in[1];
    const float* bxh0 = (const float*)d_in[2];
    const float* whh0 = (const float*)d_in[3];
    const float* bhh0 = (const float*)d_in[4];
    const float* wxh1 = (const float*)d_in[5];
    const float* bxh1 = (const float*)d_in[6];
    const float* whh1 = (const float*)d_in[7];
    const float* bhh1 = (const float*)d_in[8];
    float* out = (float*)d_out;

    char* ws = (char*)d_ws;
    unsigned short* h0b  = (unsigned short*)(ws);
    unsigned short* h1b  = (unsigned short*)(ws + 131072);
    unsigned int*   bar  = (unsigned int*)(ws + 262144);
    unsigned short* wx0b = (unsigned short*)(ws + 266240);
    unsigned short* wh0b = (unsigned short*)(ws + 1314816);
    unsigned short* wx1b = (unsigned short*)(ws + 3411968);
    unsigned short* wh1b = (unsigned short*)(ws + 5509120);

    lstm_prep<<<dim3(512), dim3(256), 0, stream>>>(
        wxh0, whh0, wxh1, whh1, wx0b, wh0b, wx1b, wh1b, (unsigned int*)ws);

    lstm_main<<<dim3(NBLK), dim3(256), 0, stream>>>(
        x, wx0b, wh0b, wx1b, wh1b, bxh0, bhh0, bxh1, bhh1,
        out, h0b, h1b, bar);
}